// Round 12
// baseline (1110.445 us; speedup 1.0000x reference)
//
#include <hip/hip_runtime.h>

// RetinaNet head, bf16 implicit-GEMM conv3x3 via MFMA 16x16x32.
// Round 12: R11 + 8-wave (512-thr) cls-out with 256-co tiles.
//   720 = 3*256 exactly -> zero co-padding (was 768, 6.7% waste);
//   A staged once per 256 co (restage cost/FLOP halves);
//   LDS 80KB (A 32K + 3x16K B) -> 2 blocks/CU = 16 waves/CU (was 12);
//   R4 counted-vmcnt 3-deep schedule (identical per-wave issue cadence);
//   bijective XCD chunking for grid 1284 (8 chunks of 161/160).
// Towers (R4 core), reg-out (R2 core), preps: unchanged from R11.
// Packed B: towers/reg-out [nt][cc][tap][co128][p4][8bf]; cls-out
// [nt3][cc][tap][co256][p4][8bf]. Piece pre-XOR-swizzled by ((co>>1)&3).
// A staged linear via global_load_lds, read with XOR ((pos>>1)&3)<<4.

typedef __bf16 v8bf __attribute__((ext_vector_type(8)));
typedef float f32x4 __attribute__((ext_vector_type(4)));

__device__ __forceinline__ v8bf zero8() {
  v8bf v;
#pragma unroll
  for (int j = 0; j < 8; ++j) v[j] = (__bf16)0.0f;
  return v;
}

__device__ __forceinline__ void glds16(const void* g, void* l) {
  __builtin_amdgcn_global_load_lds((const __attribute__((address_space(1))) unsigned int*)g,
                                   (__attribute__((address_space(3))) unsigned int*)l, 16, 0, 0);
}

struct Geo { int W, H, HW, pbase, obC, obR, t; };

// 128px tiling: 107 tiles/n (79/20/5/2/1)
__device__ __forceinline__ Geo decode128(int r) {
  Geo g;
  if (r < 79)       { g.W=100;g.H=100;g.HW=10000;g.pbase=0;     g.obC=0;       g.obR=0;      g.t=r; }
  else if (r < 99)  { g.W=50; g.H=50; g.HW=2500; g.pbase=40000; g.obC=7200000; g.obR=360000; g.t=r-79; }
  else if (r < 104) { g.W=25; g.H=25; g.HW=625;  g.pbase=50000; g.obC=9000000; g.obR=450000; g.t=r-99; }
  else if (r < 106) { g.W=13; g.H=13; g.HW=169;  g.pbase=52500; g.obC=9450000; g.obR=472500; g.t=r-104; }
  else              { g.W=7;  g.H=7;  g.HW=49;   g.pbase=53176; g.obC=9571680; g.obR=478584; g.t=r-106; }
  return g;
}
// 96px tiling: 142 tiles/n (105/27/7/2/1)
__device__ __forceinline__ Geo decode96(int r) {
  Geo g;
  if (r < 105)      { g.W=100;g.H=100;g.HW=10000;g.pbase=0;     g.obC=0;       g.obR=0;      g.t=r; }
  else if (r < 132) { g.W=50; g.H=50; g.HW=2500; g.pbase=40000; g.obC=7200000; g.obR=360000; g.t=r-105; }
  else if (r < 139) { g.W=25; g.H=25; g.HW=625;  g.pbase=50000; g.obC=9000000; g.obR=450000; g.t=r-132; }
  else if (r < 141) { g.W=13; g.H=13; g.HW=169;  g.pbase=52500; g.obC=9450000; g.obR=472500; g.t=r-139; }
  else              { g.W=7;  g.H=7;  g.HW=49;   g.pbase=53176; g.obC=9571680; g.obR=478584; g.t=r-141; }
  return g;
}

// ------- prep: NCHW fp32 -> NHWC bf16 (coalesced reads: pix lane-fastest) -------
__global__ __launch_bounds__(256)
void prep_in(const float* __restrict__ f0, const float* __restrict__ f1,
             const float* __restrict__ f2, const float* __restrict__ f3,
             const float* __restrict__ f4, __bf16* __restrict__ dst)
{
  int g = blockIdx.x * 256 + threadIdx.x;
  if (g >= 1712000) return;               // 32 cg * 53500 pix
  int cg = g / 53500;                     // channel octet 0..31
  int pix = g - cg * 53500;
  const float* s; int HW, hw, n;
  if (pix < 40000)      { s = f0; HW = 10000; int p = pix;         n = p / 10000; hw = p - n * 10000; }
  else if (pix < 50000) { s = f1; HW = 2500;  int p = pix - 40000; n = p / 2500;  hw = p - n * 2500;  }
  else if (pix < 52500) { s = f2; HW = 625;   int p = pix - 50000; n = p / 625;   hw = p - n * 625;   }
  else if (pix < 53176) { s = f3; HW = 169;   int p = pix - 52500; n = p / 169;   hw = p - n * 169;   }
  else                  { s = f4; HW = 49;    int p = pix - 53176; n = p / 49;    hw = p - n * 49;    }
  const float* sp = s + (n * 256 + cg * 8) * HW + hw;
  v8bf v;
#pragma unroll
  for (int j = 0; j < 8; ++j) v[j] = (__bf16)sp[j * HW];
  *(v8bf*)(dst + (size_t)pix * 256 + cg * 8) = v;
}

// ------ prep: 8 tower (128co) + cls-out (256co x3) + reg-out (128co) ------
__global__ __launch_bounds__(256)
void prep_w_all(const float* __restrict__ cls_w, const float* __restrict__ reg_w,
                const float* __restrict__ cls_ow, const float* __restrict__ reg_ow,
                __bf16* __restrict__ wb)
{
  int t = blockIdx.x * 256 + threadIdx.x;
  if (t < 589824) {                        // 8 tower tensors x 73728 octets
    int tensor = t / 73728, within = t % 73728;
    const float* src = tensor < 4 ? cls_w + tensor * 589824 : reg_w + (tensor - 4) * 589824;
    __bf16* dst = wb + (size_t)tensor * 589824;
    int p = within & 3; int xx = within >> 2;
    int co = xx & 127; xx >>= 7;
    int tap = xx % 9; xx /= 9;
    int cc = xx & 7; int nt = xx >> 3;
    int l = p ^ ((co >> 1) & 3);
    int cog = nt * 128 + co;
    v8bf v = zero8();
    const float* sp = src + ((size_t)cog * 256 + cc * 32 + l * 8) * 9 + tap;
#pragma unroll
    for (int j = 0; j < 8; ++j) v[j] = (__bf16)sp[j * 9];
    *(v8bf*)(dst + ((size_t)(((nt * 8 + cc) * 9 + tap) * 128 + co) * 32 + p * 8)) = v;
  } else if (t < 811008) {                 // cls-out 256-co: 3 x 8 x 9 x 256 x 4
    int within = t - 589824;
    int p = within & 3; int xx = within >> 2;
    int co = xx & 255; xx >>= 8;
    int tap = xx % 9; xx /= 9;
    int cc = xx & 7; int nt = xx >> 3;     // 0..2
    int l = p ^ ((co >> 1) & 3);
    int cog = nt * 256 + co;
    v8bf v = zero8();
    if (cog < 720) {
      const float* sp = cls_ow + ((size_t)cog * 256 + cc * 32 + l * 8) * 9 + tap;
#pragma unroll
      for (int j = 0; j < 8; ++j) v[j] = (__bf16)sp[j * 9];
    }
    *(v8bf*)(wb + (size_t)8 * 589824 + (size_t)nt * 589824 +
             ((size_t)((cc * 9 + tap) * 256 + co) * 32 + p * 8)) = v;
  } else {                                 // reg-out 128-co: 1 x 8 x 9 x 128 x 4
    int within = t - 811008;
    int p = within & 3; int xx = within >> 2;
    int co = xx & 127; xx >>= 7;
    int tap = xx % 9; int cc = xx / 9;
    int l = p ^ ((co >> 1) & 3);
    v8bf v = zero8();
    if (co < 36) {
      const float* sp = reg_ow + ((size_t)co * 256 + cc * 32 + l * 8) * 9 + tap;
#pragma unroll
      for (int j = 0; j < 8; ++j) v[j] = (__bf16)sp[j * 9];
    }
    *(v8bf*)(wb + (size_t)8 * 589824 + 1769472 +
             ((size_t)((cc * 9 + tap) * 128 + co) * 32 + p * 8)) = v;
  }
}

// ======== TOWER core (R4): 96px x 128co, counted vmcnt, 3-deep B ========
__device__ __forceinline__ void conv_core_t(const char* __restrict__ wsbase,
    unsigned so, unsigned zpoff, const char* __restrict__ wnt,
    int W, int H, int p0, int npx, f32x4 (&acc)[3][4])
{
  __shared__ __align__(16) char ldsA[28672];
  __shared__ __align__(16) char ldsB[24576];
  const int Wp = W + 2;
  const int pend = p0 + npx - 1;
  const int rowlo = p0 / W - 1;
  const int tid = threadIdx.x, lane = tid & 63, wv = tid >> 6;
  const int wn = wv & 1, wm = wv >> 1, la = lane & 15, kg = lane >> 4;

  unsigned offA[7];
#pragma unroll
  for (int j = 0; j < 7; ++j) {
    int pos = (wv * 7 + j) * 16 + (lane >> 2);
    int h = pos / Wp;
    int wc = pos - h * Wp - 1;
    int ar = rowlo + h;
    int pl = (lane & 3) ^ ((pos >> 1) & 3);
    bool ok = (ar >= 0) & (ar < H) & (wc >= 0) & (wc < W);
    offA[j] = ok ? (so + (unsigned)(ar * W + wc) * 512u + (unsigned)pl * 16u)
                 : (zpoff + (unsigned)(lane & 3) * 16u);
  }

  int pos0[3], fvalid[3];
#pragma unroll
  for (int f = 0; f < 3; ++f) {
    int fg = wm * 3 + f;
    fvalid[f] = (fg * 16 < npx);
    int p = p0 + fg * 16 + la; if (p > pend) p = pend;
    int h = p / W;
    pos0[f] = (h - rowlo) * Wp + (p - h * W + 1);
  }

  int boff[4];
#pragma unroll
  for (int nj = 0; nj < 4; ++nj) {
    int co = wn * 64 + nj * 16 + la;
    boff[nj] = (co << 6) + ((kg << 4) ^ (((co >> 1) & 3) << 4));
  }

  const char* bq = wnt + wv * 2048 + lane * 16;
  char* bd = (char*)ldsB + wv * 2048;

#pragma unroll
  for (int j = 0; j < 7; ++j) { glds16(wsbase + offA[j], (char*)ldsA + (wv * 7 + j) * 1024); offA[j] += 64u; }
  glds16(bq, bd); glds16(bq + 1024, bd + 1024);
  glds16(bq + 8192, bd + 8192); glds16(bq + 9216, bd + 9216);

  for (int cc = 0; cc < 8; ++cc) {
#pragma unroll
    for (int tap = 0; tap < 9; ++tap) {
      if (tap == 8) {
        if (cc == 7) { asm volatile("s_waitcnt vmcnt(0)" ::: "memory"); }
        else         { asm volatile("s_waitcnt vmcnt(2)" ::: "memory"); }
      } else         { asm volatile("s_waitcnt vmcnt(2)" ::: "memory"); }
      __builtin_amdgcn_s_barrier();
      if (tap == 0 && cc > 0) {
#pragma unroll
        for (int j = 0; j < 7; ++j) { glds16(wsbase + offA[j], (char*)ldsA + (wv * 7 + j) * 1024); offA[j] += 64u; }
        const char* bs = bq + (cc * 9 + 2) * 8192;
        glds16(bs, bd + 16384); glds16(bs + 1024, bd + 17408);
        asm volatile("s_waitcnt vmcnt(2)" ::: "memory");
        __builtin_amdgcn_s_barrier();
      } else {
        int q = cc * 9 + tap;
        if (q < 70) {
          const char* bs = bq + (q + 2) * 8192;
          char* d = bd + ((tap + 2) % 3) * 8192;
          glds16(bs, d); glds16(bs + 1024, d + 1024);
        }
      }
      const char* bbuf = (const char*)ldsB + (tap % 3) * 8192;
      v8bf bfr[4];
#pragma unroll
      for (int nj = 0; nj < 4; ++nj) bfr[nj] = *(const v8bf*)(bbuf + boff[nj]);
      const int dh = tap / 3 - 1, dw = tap % 3 - 1;
      const int dt = dh * Wp + dw;
      v8bf afr[3];
#pragma unroll
      for (int f = 0; f < 3; ++f)
        if (fvalid[f]) {
          int pos = pos0[f] + dt;
          afr[f] = *(const v8bf*)((const char*)ldsA + ((pos << 6) + ((kg << 4) ^ (((pos >> 1) & 3) << 4))));
        }
      __builtin_amdgcn_s_setprio(1);
#pragma unroll
      for (int f = 0; f < 3; ++f)
        if (fvalid[f])
#pragma unroll
          for (int nj = 0; nj < 4; ++nj)
            acc[f][nj] = __builtin_amdgcn_mfma_f32_16x16x32_bf16(afr[f], bfr[nj], acc[f][nj], 0, 0, 0);
      __builtin_amdgcn_s_setprio(0);
    }
  }
}

// ======== OUT core (R2): 128px x 128co, per-tap drain, 2-deep B ========
__device__ __forceinline__ void conv_core_o(const char* __restrict__ wsbase,
    unsigned so, unsigned zpoff, const char* __restrict__ wnt,
    int W, int H, int p0, int npx, f32x4 (&acc)[4][4])
{
  __shared__ __align__(16) char ldsA[32768];
  __shared__ __align__(16) char ldsB[16384];
  const int Wp = W + 2;
  const int pend = p0 + npx - 1;
  const int rowlo = p0 / W - 1;
  const int tid = threadIdx.x, lane = tid & 63, wv = tid >> 6;
  const int wn = wv & 1, wm = wv >> 1, la = lane & 15, kg = lane >> 4;
  const int i0 = wv * 8;

  unsigned offA[8];
#pragma unroll
  for (int j = 0; j < 8; ++j) {
    int pos = (i0 + j) * 16 + (lane >> 2);
    int h = pos / Wp;
    int wc = pos - h * Wp - 1;
    int ar = rowlo + h;
    int pl = (lane & 3) ^ ((pos >> 1) & 3);
    bool ok = (ar >= 0) & (ar < H) & (wc >= 0) & (wc < W);
    offA[j] = ok ? (so + (unsigned)(ar * W + wc) * 512u + (unsigned)pl * 16u)
                 : (zpoff + (unsigned)(lane & 3) * 16u);
  }

  int pos0[4], fvalid[4];
#pragma unroll
  for (int f = 0; f < 4; ++f) {
    int fg = wm * 4 + f;
    fvalid[f] = (fg * 16 < npx);
    int p = p0 + fg * 16 + la; if (p > pend) p = pend;
    int h = p / W;
    pos0[f] = (h - rowlo) * Wp + (p - h * W + 1);
  }

  int boff[4];
#pragma unroll
  for (int nj = 0; nj < 4; ++nj) {
    int co = wn * 64 + nj * 16 + la;
    boff[nj] = (co << 6) + ((kg << 4) ^ (((co >> 1) & 3) << 4));
  }

  const char* bq = wnt + wv * 2048 + lane * 16;
  char* bd = (char*)ldsB + wv * 2048;

#define ISSUE_AO() do { _Pragma("unroll") \
    for (int j = 0; j < 8; ++j) { glds16(wsbase + offA[j], (char*)ldsA + (i0 + j) * 1024); offA[j] += 64u; } } while (0)
#define ISSUE_BO(q_, buf_) do { const char* s_ = bq + (q_) * 8192; \
    char* d_ = bd + (buf_) * 8192; \
    glds16(s_, d_); glds16(s_ + 1024, d_ + 1024); } while (0)

  ISSUE_AO();
  ISSUE_BO(0, 0);
  int pb = 0;

  for (int cc = 0; cc < 8; ++cc) {
#pragma unroll
    for (int tap = 0; tap < 9; ++tap) {
      __syncthreads();
      int q = cc * 9 + tap;
      if (q < 71) ISSUE_BO(q + 1, pb ^ 1);
      v8bf bfr[4];
#pragma unroll
      for (int nj = 0; nj < 4; ++nj) bfr[nj] = *(const v8bf*)((const char*)ldsB + pb * 8192 + boff[nj]);
      const int dh = tap / 3 - 1, dw = tap % 3 - 1;
      const int dt = dh * Wp + dw;
      v8bf afr[4];
#pragma unroll
      for (int f = 0; f < 4; ++f)
        if (fvalid[f]) {
          int pos = pos0[f] + dt;
          afr[f] = *(const v8bf*)((const char*)ldsA + ((pos << 6) + ((kg << 4) ^ (((pos >> 1) & 3) << 4))));
        }
#pragma unroll
      for (int f = 0; f < 4; ++f)
        if (fvalid[f])
#pragma unroll
          for (int nj = 0; nj < 4; ++nj)
            acc[f][nj] = __builtin_amdgcn_mfma_f32_16x16x32_bf16(afr[f], bfr[nj], acc[f][nj], 0, 0, 0);
      pb ^= 1;
      if (tap == 8 && cc < 7) { __syncthreads(); ISSUE_AO(); }
    }
  }
#undef ISSUE_AO
#undef ISSUE_BO
}

// ---------------- tower conv (96px, R4 kernel), dual-branch ----------------
__global__ __launch_bounds__(256, 2)
void conv_tower(const char* __restrict__ wsbase,
                unsigned so0, __bf16* __restrict__ dst0, const __bf16* __restrict__ w0, const float* __restrict__ b0,
                unsigned so1, __bf16* __restrict__ dst1, const __bf16* __restrict__ w1, const float* __restrict__ b1,
                unsigned zpoff, int half)
{
  int bid = blockIdx.x;
  int br = bid >= half;
  bid -= br ? half : 0;
  unsigned soff = br ? so1 : so0;
  __bf16* dst = br ? dst1 : dst0;
  const __bf16* wt = br ? w1 : w0;
  const float* bias = br ? b1 : b0;

  int x = bid & 7, slot = bid >> 3;        // XCD swizzle: nt twins colocated
  int nt = slot & 1, mtl = slot >> 1;
  int mt = x + (mtl << 3);
  int n = mt / 142, r = mt - n * 142;
  Geo g = decode96(r);
  int p0 = g.t * 96;
  int npx = g.HW - p0; if (npx > 96) npx = 96;
  unsigned so = soff + (unsigned)(g.pbase + n * g.HW) * 512u;

  f32x4 acc[3][4];
#pragma unroll
  for (int f = 0; f < 3; ++f)
#pragma unroll
    for (int j = 0; j < 4; ++j)
#pragma unroll
      for (int k = 0; k < 4; ++k) acc[f][j][k] = 0.0f;

  conv_core_t(wsbase, so, zpoff, (const char*)(wt + nt * 294912), g.W, g.H, p0, npx, acc);

  int lane = threadIdx.x & 63, wv = threadIdx.x >> 6;
  int wm = wv >> 1, wn = wv & 1, la = lane & 15, kg = lane >> 4;
  size_t pixbase = (size_t)(g.pbase + n * g.HW + p0);
#pragma unroll
  for (int f = 0; f < 3; ++f) {
    int fg = wm * 3 + f;
    if (fg * 16 < npx) {
#pragma unroll
      for (int nj = 0; nj < 4; ++nj) {
        int cob = nt * 128 + wn * 64 + nj * 16 + la;
        float bs = bias[cob];
#pragma unroll
        for (int rr = 0; rr < 4; ++rr) {
          int pl = fg * 16 + kg * 4 + rr;
          if (pl < npx)
            dst[((pixbase + pl) << 8) + cob] = (__bf16)fmaxf(acc[f][nj][rr] + bs, 0.0f);
        }
      }
    }
  }
}

// ==== cls out conv: 8-wave 512-thr, 128px x 256co, counted vmcnt 3-deep ====
__global__ __launch_bounds__(512, 4)
void conv_cls_out(const char* __restrict__ wsbase, unsigned soA,
                  float* __restrict__ out, const __bf16* __restrict__ wco,
                  const float* __restrict__ bco, unsigned zpoff)
{
  __shared__ __align__(16) char ldsA[32768];   // 512 pos * 64B
  __shared__ __align__(16) char ldsB[49152];   // 3 bufs * 16KB (one tap, 256 co)

  // bijective XCD chunking for 1284 blocks (8 chunks: 4x161 + 4x160)
  int bid0 = blockIdx.x;
  int x = bid0 & 7, i = bid0 >> 3;
  int w = (x < 4) ? (x * 161 + i) : (644 + (x - 4) * 160 + i);
  int nt = w % 3, mt = w / 3;
  int n = mt / 107, r = mt - n * 107;
  Geo g = decode128(r);
  int p0 = g.t << 7;
  int npx = g.HW - p0; if (npx > 128) npx = 128;
  unsigned so = soA + (unsigned)(g.pbase + n * g.HW) * 512u;
  const char* wnt = (const char*)(wco + (size_t)nt * 589824);

  const int Wp = g.W + 2;
  const int pend = p0 + npx - 1;
  const int rowlo = p0 / g.W - 1;
  const int tid = threadIdx.x, lane = tid & 63, wv = tid >> 6;   // wv 0..7
  const int wm = wv >> 2, wn = wv & 3, la = lane & 15, kg = lane >> 4;

  // A: 4 glds/wave (8 waves x 4 x 64 lanes = 2048 x 16B = 32KB)
  unsigned offA[4];
#pragma unroll
  for (int j = 0; j < 4; ++j) {
    int pos = (wv * 4 + j) * 16 + (lane >> 2);
    int h = pos / Wp;
    int wc = pos - h * Wp - 1;
    int ar = rowlo + h;
    int pl = (lane & 3) ^ ((pos >> 1) & 3);
    bool ok = (ar >= 0) & (ar < g.H) & (wc >= 0) & (wc < g.W);
    offA[j] = ok ? (so + (unsigned)(ar * g.W + wc) * 512u + (unsigned)pl * 16u)
                 : (zpoff + (unsigned)(lane & 3) * 16u);
  }

  int pos0[4], fvalid[4];
#pragma unroll
  for (int f = 0; f < 4; ++f) {
    int fg = wm * 4 + f;
    fvalid[f] = (fg * 16 < npx);
    int p = p0 + fg * 16 + la; if (p > pend) p = pend;
    int h = p / g.W;
    pos0[f] = (h - rowlo) * Wp + (p - h * g.W + 1);
  }

  int boff[4];
#pragma unroll
  for (int nj = 0; nj < 4; ++nj) {
    int co = wn * 64 + nj * 16 + la;              // 0..255
    boff[nj] = (co << 6) + ((kg << 4) ^ (((co >> 1) & 3) << 4));
  }

  const char* bq = wnt + wv * 2048 + lane * 16;   // per-wave B src slice (2KB of 16KB)
  char* bd = (char*)ldsB + wv * 2048;

  f32x4 acc[4][4];
#pragma unroll
  for (int f = 0; f < 4; ++f)
#pragma unroll
    for (int j = 0; j < 4; ++j)
#pragma unroll
      for (int k = 0; k < 4; ++k) acc[f][j][k] = 0.0f;

  // prologue: A x4 + B(0) x2 + B(1) x2
#pragma unroll
  for (int j = 0; j < 4; ++j) { glds16(wsbase + offA[j], (char*)ldsA + (wv * 4 + j) * 1024); offA[j] += 64u; }
  glds16(bq, bd); glds16(bq + 1024, bd + 1024);
  glds16(bq + 16384, bd + 16384); glds16(bq + 17408, bd + 17408);

  for (int cc = 0; cc < 8; ++cc) {
#pragma unroll
    for (int tap = 0; tap < 9; ++tap) {
      if (tap == 8) {
        if (cc == 7) { asm volatile("s_waitcnt vmcnt(0)" ::: "memory"); }
        else         { asm volatile("s_waitcnt vmcnt(2)" ::: "memory"); }
      } else         { asm volatile("s_waitcnt vmcnt(2)" ::: "memory"); }
      __builtin_amdgcn_s_barrier();
      if (tap == 0 && cc > 0) {
#pragma unroll
        for (int j = 0; j < 4; ++j) { glds16(wsbase + offA[j], (char*)ldsA + (wv * 4 + j) * 1024); offA[j] += 64u; }
        const char* bs = bq + (size_t)(cc * 9 + 2) * 16384;
        glds16(bs, bd + 32768); glds16(bs + 1024, bd + 33792);
        asm volatile("s_waitcnt vmcnt(2)" ::: "memory");
        __builtin_amdgcn_s_barrier();
      } else {
        int q = cc * 9 + tap;
        if (q < 70) {
          const char* bs = bq + (size_t)(q + 2) * 16384;
          char* d = bd + ((tap + 2) % 3) * 16384;
          glds16(bs, d); glds16(bs + 1024, d + 1024);
        }
      }
      const char* bbuf = (const char*)ldsB + (tap % 3) * 16384;
      v8bf bfr[4];
#pragma unroll
      for (int nj = 0; nj < 4; ++nj) bfr[nj] = *(const v8bf*)(bbuf + boff[nj]);
      const int dh = tap / 3 - 1, dw = tap % 3 - 1;
      const int dt = dh * Wp + dw;
      v8bf afr[4];
#pragma unroll
      for (int f = 0; f < 4; ++f)
        if (fvalid[f]) {
          int pos = pos0[f] + dt;
          afr[f] = *(const v8bf*)((const char*)ldsA + ((pos << 6) + ((kg << 4) ^ (((pos >> 1) & 3) << 4))));
        }
      __builtin_amdgcn_s_setprio(1);
#pragma unroll
      for (int f = 0; f < 4; ++f)
        if (fvalid[f])
#pragma unroll
          for (int nj = 0; nj < 4; ++nj)
            acc[f][nj] = __builtin_amdgcn_mfma_f32_16x16x32_bf16(afr[f], bfr[nj], acc[f][nj], 0, 0, 0);
      __builtin_amdgcn_s_setprio(0);
    }
  }

#pragma unroll
  for (int f = 0; f < 4; ++f) {
    int fg = wm * 4 + f;
    if (fg * 16 < npx) {
#pragma unroll
      for (int nj = 0; nj < 4; ++nj) {
        int cob = nt * 256 + wn * 64 + nj * 16 + la;
        if (cob < 720) {
          float bs = bco[cob];
#pragma unroll
          for (int rr = 0; rr < 4; ++rr) {
            int pl = fg * 16 + kg * 4 + rr;
            if (pl < npx) {
              int pix = p0 + pl;
              out[(size_t)n * 9606960 + g.obC + (size_t)pix * 720 + cob] = acc[f][nj][rr] + bs;
            }
          }
        }
      }
    }
  }
}

// ---------------- reg out conv (128px, R2 kernel), grid 428 ----------------
__global__ __launch_bounds__(256, 3)
void conv_reg_out(const char* __restrict__ wsbase, unsigned soA,
                  float* __restrict__ out, const __bf16* __restrict__ wro,
                  const float* __restrict__ bro, unsigned zpoff)
{
  int mt = blockIdx.x;
  int n = mt / 107, r = mt - n * 107;
  Geo g = decode128(r);
  int p0 = g.t << 7;
  int npx = g.HW - p0; if (npx > 128) npx = 128;
  unsigned so = soA + (unsigned)(g.pbase + n * g.HW) * 512u;

  f32x4 acc[4][4];
#pragma unroll
  for (int f = 0; f < 4; ++f)
#pragma unroll
    for (int j = 0; j < 4; ++j)
#pragma unroll
      for (int k = 0; k < 4; ++k) acc[f][j][k] = 0.0f;

  conv_core_o(wsbase, so, zpoff, (const char*)wro, g.W, g.H, p0, npx, acc);

  int lane = threadIdx.x & 63, wv = threadIdx.x >> 6;
  int wm = wv >> 1, wn = wv & 1, la = lane & 15, kg = lane >> 4;
#pragma unroll
  for (int f = 0; f < 4; ++f) {
    int fg = wm * 4 + f;
    if (fg * 16 < npx) {
#pragma unroll
      for (int nj = 0; nj < 4; ++nj) {
        int cob = wn * 64 + nj * 16 + la;
        if (cob < 36) {
#pragma unroll
          for (int rr = 0; rr < 4; ++rr) {
            int pl = fg * 16 + kg * 4 + rr;
            if (pl < npx) {
              int pix = p0 + pl;
              out[38427840 + (size_t)n * 480348 + g.obR + (size_t)pix * 36 + cob] = acc[f][nj][rr] + bro[cob];
            }
          }
        }
      }
    }
  }
}

extern "C" void kernel_launch(void* const* d_in, const int* in_sizes, int n_in,
                              void* d_out, int out_size, void* d_ws, size_t ws_size,
                              hipStream_t stream) {
  (void)in_sizes; (void)n_in; (void)out_size;
  const float* feat0 = (const float*)d_in[0];
  const float* feat1 = (const float*)d_in[1];
  const float* feat2 = (const float*)d_in[2];
  const float* feat3 = (const float*)d_in[3];
  const float* feat4 = (const float*)d_in[4];
  const float* cls_w  = (const float*)d_in[5];
  const float* cls_b  = (const float*)d_in[6];
  const float* cls_ow = (const float*)d_in[7];
  const float* cls_ob = (const float*)d_in[8];
  const float* reg_w  = (const float*)d_in[9];
  const float* reg_b  = (const float*)d_in[10];
  const float* reg_ow = (const float*)d_in[11];
  const float* reg_ob = (const float*)d_in[12];
  float* out = (float*)d_out;

  const size_t ACT = 13663232;             // bf16 elems per activation tensor
  const size_t WSEG = 6782976;             // packed weights total elems
  const char* wsbase = (const char*)d_ws;
  __bf16* base = (__bf16*)d_ws;

  bool fused = ws_size >= (5 * ACT + WSEG + 4096) * 2;
  int nact = fused ? 5 : 3;
  __bf16* A = base + ACT;
  __bf16* B = base + 2 * ACT;
  __bf16* C = fused ? base + 3 * ACT : A;
  __bf16* D = fused ? base + 4 * ACT : B;
  __bf16* wb = base + nact * ACT;

  __bf16* w_cls[4], *w_reg[4];
  for (int li = 0; li < 4; ++li) { w_cls[li] = wb + (size_t)li * 589824; w_reg[li] = wb + (size_t)(4 + li) * 589824; }
  __bf16* wco = wb + 8 * 589824;           // 3 x 589824 (256-co layout)
  __bf16* wro = wco + 1769472;
  __bf16* zp = wro + 294912;

  unsigned off_in = 0;
  unsigned off_A = (unsigned)(ACT * 2);
  unsigned off_B = (unsigned)(ACT * 4);
  unsigned off_C = fused ? (unsigned)(ACT * 6) : off_A;
  unsigned off_D = fused ? (unsigned)(ACT * 8) : off_B;
  unsigned off_zp = (unsigned)((nact * ACT + WSEG) * 2);

  hipMemsetAsync(zp, 0, 8192, stream);
  prep_in<<<6688, 256, 0, stream>>>(feat0, feat1, feat2, feat3, feat4, base);
  prep_w_all<<<3312, 256, 0, stream>>>(cls_w, reg_w, cls_ow, reg_ow, wb);

  if (fused) {
    conv_tower<<<2272, 256, 0, stream>>>(wsbase, off_in, A, w_cls[0], cls_b + 0,   off_in, C, w_reg[0], reg_b + 0,   off_zp, 1136);
    conv_tower<<<2272, 256, 0, stream>>>(wsbase, off_A,  B, w_cls[1], cls_b + 256, off_C,  D, w_reg[1], reg_b + 256, off_zp, 1136);
    conv_tower<<<2272, 256, 0, stream>>>(wsbase, off_B,  A, w_cls[2], cls_b + 512, off_D,  C, w_reg[2], reg_b + 512, off_zp, 1136);
    // L4: reg half first, cls half second (cls-out input written last)
    conv_tower<<<2272, 256, 0, stream>>>(wsbase, off_C,  D, w_reg[3], reg_b + 768, off_A,  B, w_cls[3], cls_b + 768, off_zp, 1136);
    conv_cls_out<<<1284, 512, 0, stream>>>(wsbase, off_B, out, wco, cls_ob, off_zp);
    conv_reg_out<<<428, 256, 0, stream>>>(wsbase, off_D, out, wro, reg_ob, off_zp);
  } else {
    conv_tower<<<1136, 256, 0, stream>>>(wsbase, off_in, A, w_cls[0], cls_b + 0,   off_in, A, w_cls[0], cls_b, off_zp, 1136);
    conv_tower<<<1136, 256, 0, stream>>>(wsbase, off_A,  B, w_cls[1], cls_b + 256, off_A,  B, w_cls[1], cls_b, off_zp, 1136);
    conv_tower<<<1136, 256, 0, stream>>>(wsbase, off_B,  A, w_cls[2], cls_b + 512, off_B,  A, w_cls[2], cls_b, off_zp, 1136);
    conv_tower<<<1136, 256, 0, stream>>>(wsbase, off_A,  B, w_cls[3], cls_b + 768, off_A,  B, w_cls[3], cls_b, off_zp, 1136);
    conv_cls_out<<<1284, 512, 0, stream>>>(wsbase, off_B, out, wco, cls_ob, off_zp);
    conv_tower<<<1136, 256, 0, stream>>>(wsbase, off_in, A, w_reg[0], reg_b + 0,   off_in, A, w_reg[0], reg_b, off_zp, 1136);
    conv_tower<<<1136, 256, 0, stream>>>(wsbase, off_A,  B, w_reg[1], reg_b + 256, off_A,  B, w_reg[1], reg_b, off_zp, 1136);
    conv_tower<<<1136, 256, 0, stream>>>(wsbase, off_B,  A, w_reg[2], reg_b + 512, off_B,  A, w_reg[2], reg_b, off_zp, 1136);
    conv_tower<<<1136, 256, 0, stream>>>(wsbase, off_A,  B, w_reg[3], reg_b + 768, off_A,  B, w_reg[3], reg_b, off_zp, 1136);
    conv_reg_out<<<428, 256, 0, stream>>>(wsbase, off_B, out, wro, reg_ob, off_zp);
  }
}

// Round 13
// 998.934 us; speedup vs baseline: 1.1116x; 1.1116x over previous
//
#include <hip/hip_runtime.h>

// RetinaNet head, bf16 implicit-GEMM conv3x3 via MFMA 16x16x32.
// FINAL (= Round 11, best measured 991.5us):
//  - prep_in: coalesced cg-major mapping (lanes walk pix; fp32 reads contiguous).
//  - Towers: R4 core (counted vmcnt(2), 3-deep B, setprio, 96px, 52KB LDS,
//    3 blk/CU, twin-colocating XCD swizzle, dual-branch fused grid 2272).
//  - cls-out: R2 core (per-tap drain, 2-deep B, 128px, 48KB, 3 blk/CU),
//    grid 2568, bijective XCD chunking (bid=(bid0&7)*321+(bid0>>3)) ->
//    6 nt-siblings share one XCD's L2 (FETCH 137->72MB).
//  - reg-out: R2 core, grid 428, launched last.
//  - L4 dual: reg half first, cls half second (cls-out input written last).
// Packed B layout per tensor: [nt][cc 8][tap 9][co 128][piece 4][8 bf16],
// piece pre-XOR-swizzled by ((co>>1)&3). A staged linear via global_load_lds,
// read with involutive XOR ((pos>>1)&3)<<4.

typedef __bf16 v8bf __attribute__((ext_vector_type(8)));
typedef float f32x4 __attribute__((ext_vector_type(4)));

__device__ __forceinline__ v8bf zero8() {
  v8bf v;
#pragma unroll
  for (int j = 0; j < 8; ++j) v[j] = (__bf16)0.0f;
  return v;
}

__device__ __forceinline__ void glds16(const void* g, void* l) {
  __builtin_amdgcn_global_load_lds((const __attribute__((address_space(1))) unsigned int*)g,
                                   (__attribute__((address_space(3))) unsigned int*)l, 16, 0, 0);
}

struct Geo { int W, H, HW, pbase, obC, obR, t; };

// 128px tiling: 107 tiles/n (79/20/5/2/1)
__device__ __forceinline__ Geo decode128(int r) {
  Geo g;
  if (r < 79)       { g.W=100;g.H=100;g.HW=10000;g.pbase=0;     g.obC=0;       g.obR=0;      g.t=r; }
  else if (r < 99)  { g.W=50; g.H=50; g.HW=2500; g.pbase=40000; g.obC=7200000; g.obR=360000; g.t=r-79; }
  else if (r < 104) { g.W=25; g.H=25; g.HW=625;  g.pbase=50000; g.obC=9000000; g.obR=450000; g.t=r-99; }
  else if (r < 106) { g.W=13; g.H=13; g.HW=169;  g.pbase=52500; g.obC=9450000; g.obR=472500; g.t=r-104; }
  else              { g.W=7;  g.H=7;  g.HW=49;   g.pbase=53176; g.obC=9571680; g.obR=478584; g.t=r-106; }
  return g;
}
// 96px tiling: 142 tiles/n (105/27/7/2/1)
__device__ __forceinline__ Geo decode96(int r) {
  Geo g;
  if (r < 105)      { g.W=100;g.H=100;g.HW=10000;g.pbase=0;     g.obC=0;       g.obR=0;      g.t=r; }
  else if (r < 132) { g.W=50; g.H=50; g.HW=2500; g.pbase=40000; g.obC=7200000; g.obR=360000; g.t=r-105; }
  else if (r < 139) { g.W=25; g.H=25; g.HW=625;  g.pbase=50000; g.obC=9000000; g.obR=450000; g.t=r-132; }
  else if (r < 141) { g.W=13; g.H=13; g.HW=169;  g.pbase=52500; g.obC=9450000; g.obR=472500; g.t=r-139; }
  else              { g.W=7;  g.H=7;  g.HW=49;   g.pbase=53176; g.obC=9571680; g.obR=478584; g.t=r-141; }
  return g;
}

// ------- prep: NCHW fp32 -> NHWC bf16 (coalesced reads: pix lane-fastest) -------
__global__ __launch_bounds__(256)
void prep_in(const float* __restrict__ f0, const float* __restrict__ f1,
             const float* __restrict__ f2, const float* __restrict__ f3,
             const float* __restrict__ f4, __bf16* __restrict__ dst)
{
  int g = blockIdx.x * 256 + threadIdx.x;
  if (g >= 1712000) return;               // 32 cg * 53500 pix
  int cg = g / 53500;                     // channel octet 0..31
  int pix = g - cg * 53500;
  const float* s; int HW, hw, n;
  if (pix < 40000)      { s = f0; HW = 10000; int p = pix;         n = p / 10000; hw = p - n * 10000; }
  else if (pix < 50000) { s = f1; HW = 2500;  int p = pix - 40000; n = p / 2500;  hw = p - n * 2500;  }
  else if (pix < 52500) { s = f2; HW = 625;   int p = pix - 50000; n = p / 625;   hw = p - n * 625;   }
  else if (pix < 53176) { s = f3; HW = 169;   int p = pix - 52500; n = p / 169;   hw = p - n * 169;   }
  else                  { s = f4; HW = 49;    int p = pix - 53176; n = p / 49;    hw = p - n * 49;    }
  const float* sp = s + (n * 256 + cg * 8) * HW + hw;
  v8bf v;
#pragma unroll
  for (int j = 0; j < 8; ++j) v[j] = (__bf16)sp[j * HW];
  *(v8bf*)(dst + (size_t)pix * 256 + cg * 8) = v;
}

// ------ prep: all 10 weight tensors, OIHW fp32 -> packed B bf16 ------
__global__ __launch_bounds__(256)
void prep_w_all(const float* __restrict__ cls_w, const float* __restrict__ reg_w,
                const float* __restrict__ cls_ow, const float* __restrict__ reg_ow,
                __bf16* __restrict__ wb)
{
  int t = blockIdx.x * 256 + threadIdx.x;
  const float* src; __bf16* dst; int CO, within;
  if (t < 589824) {                        // 8 tower tensors x 73728 octets
    int tensor = t / 73728; within = t % 73728;
    src = tensor < 4 ? cls_w + tensor * 589824 : reg_w + (tensor - 4) * 589824;
    dst = wb + (size_t)tensor * 589824; CO = 256;
  } else if (t < 811008) {                 // cls-out: 6*8*9*128*4
    within = t - 589824; src = cls_ow; dst = wb + 8 * 589824; CO = 720;
  } else {                                 // reg-out: 1*8*9*128*4
    within = t - 811008; src = reg_ow; dst = wb + 8 * 589824 + 1769472; CO = 36;
  }
  int p = within & 3; int xx = within >> 2;
  int co = xx & 127; xx >>= 7;
  int tap = xx % 9; xx /= 9;
  int cc = xx & 7; int nt = xx >> 3;
  int l = p ^ ((co >> 1) & 3);            // logical piece held at physical p
  int cog = nt * 128 + co;
  v8bf v = zero8();
  if (cog < CO) {
    const float* sp = src + ((size_t)cog * 256 + cc * 32 + l * 8) * 9 + tap;
#pragma unroll
    for (int j = 0; j < 8; ++j) v[j] = (__bf16)sp[j * 9];
  }
  *(v8bf*)(dst + ((size_t)(((nt * 8 + cc) * 9 + tap) * 128 + co) * 32 + p * 8)) = v;
}

// ======== TOWER core (R4): 96px x 128co, counted vmcnt, 3-deep B ========
__device__ __forceinline__ void conv_core_t(const char* __restrict__ wsbase,
    unsigned so, unsigned zpoff, const char* __restrict__ wnt,
    int W, int H, int p0, int npx, f32x4 (&acc)[3][4])
{
  __shared__ __align__(16) char ldsA[28672];   // 448 pos * 64B
  __shared__ __align__(16) char ldsB[24576];   // 3 bufs * 8KB (one tap each)
  const int Wp = W + 2;
  const int pend = p0 + npx - 1;
  const int rowlo = p0 / W - 1;
  const int tid = threadIdx.x, lane = tid & 63, wv = tid >> 6;
  const int wn = wv & 1, wm = wv >> 1, la = lane & 15, kg = lane >> 4;

  unsigned offA[7];
#pragma unroll
  for (int j = 0; j < 7; ++j) {
    int pos = (wv * 7 + j) * 16 + (lane >> 2);
    int h = pos / Wp;
    int wc = pos - h * Wp - 1;
    int ar = rowlo + h;
    int pl = (lane & 3) ^ ((pos >> 1) & 3);
    bool ok = (ar >= 0) & (ar < H) & (wc >= 0) & (wc < W);
    offA[j] = ok ? (so + (unsigned)(ar * W + wc) * 512u + (unsigned)pl * 16u)
                 : (zpoff + (unsigned)(lane & 3) * 16u);
  }

  int pos0[3], fvalid[3];
#pragma unroll
  for (int f = 0; f < 3; ++f) {
    int fg = wm * 3 + f;
    fvalid[f] = (fg * 16 < npx);
    int p = p0 + fg * 16 + la; if (p > pend) p = pend;
    int h = p / W;
    pos0[f] = (h - rowlo) * Wp + (p - h * W + 1);
  }

  int boff[4];
#pragma unroll
  for (int nj = 0; nj < 4; ++nj) {
    int co = wn * 64 + nj * 16 + la;
    boff[nj] = (co << 6) + ((kg << 4) ^ (((co >> 1) & 3) << 4));
  }

  const char* bq = wnt + wv * 2048 + lane * 16;
  char* bd = (char*)ldsB + wv * 2048;

#pragma unroll
  for (int j = 0; j < 7; ++j) { glds16(wsbase + offA[j], (char*)ldsA + (wv * 7 + j) * 1024); offA[j] += 64u; }
  glds16(bq, bd); glds16(bq + 1024, bd + 1024);
  glds16(bq + 8192, bd + 8192); glds16(bq + 9216, bd + 9216);

  for (int cc = 0; cc < 8; ++cc) {
#pragma unroll
    for (int tap = 0; tap < 9; ++tap) {
      if (tap == 8) {
        if (cc == 7) { asm volatile("s_waitcnt vmcnt(0)" ::: "memory"); }
        else         { asm volatile("s_waitcnt vmcnt(2)" ::: "memory"); }
      } else         { asm volatile("s_waitcnt vmcnt(2)" ::: "memory"); }
      __builtin_amdgcn_s_barrier();
      if (tap == 0 && cc > 0) {
#pragma unroll
        for (int j = 0; j < 7; ++j) { glds16(wsbase + offA[j], (char*)ldsA + (wv * 7 + j) * 1024); offA[j] += 64u; }
        const char* bs = bq + (cc * 9 + 2) * 8192;
        glds16(bs, bd + 16384); glds16(bs + 1024, bd + 17408);
        asm volatile("s_waitcnt vmcnt(2)" ::: "memory");
        __builtin_amdgcn_s_barrier();
      } else {
        int q = cc * 9 + tap;
        if (q < 70) {
          const char* bs = bq + (q + 2) * 8192;
          char* d = bd + ((tap + 2) % 3) * 8192;
          glds16(bs, d); glds16(bs + 1024, d + 1024);
        }
      }
      const char* bbuf = (const char*)ldsB + (tap % 3) * 8192;
      v8bf bfr[4];
#pragma unroll
      for (int nj = 0; nj < 4; ++nj) bfr[nj] = *(const v8bf*)(bbuf + boff[nj]);
      const int dh = tap / 3 - 1, dw = tap % 3 - 1;
      const int dt = dh * Wp + dw;
      v8bf afr[3];
#pragma unroll
      for (int f = 0; f < 3; ++f)
        if (fvalid[f]) {
          int pos = pos0[f] + dt;
          afr[f] = *(const v8bf*)((const char*)ldsA + ((pos << 6) + ((kg << 4) ^ (((pos >> 1) & 3) << 4))));
        }
      __builtin_amdgcn_s_setprio(1);
#pragma unroll
      for (int f = 0; f < 3; ++f)
        if (fvalid[f])
#pragma unroll
          for (int nj = 0; nj < 4; ++nj)
            acc[f][nj] = __builtin_amdgcn_mfma_f32_16x16x32_bf16(afr[f], bfr[nj], acc[f][nj], 0, 0, 0);
      __builtin_amdgcn_s_setprio(0);
    }
  }
}

// ======== OUT core (R2): 128px x 128co, per-tap drain, 2-deep B ========
__device__ __forceinline__ void conv_core_o(const char* __restrict__ wsbase,
    unsigned so, unsigned zpoff, const char* __restrict__ wnt,
    int W, int H, int p0, int npx, f32x4 (&acc)[4][4])
{
  __shared__ __align__(16) char ldsA[32768];   // 512 pos * 64B
  __shared__ __align__(16) char ldsB[16384];   // 2 bufs * 8KB
  const int Wp = W + 2;
  const int pend = p0 + npx - 1;
  const int rowlo = p0 / W - 1;
  const int tid = threadIdx.x, lane = tid & 63, wv = tid >> 6;
  const int wn = wv & 1, wm = wv >> 1, la = lane & 15, kg = lane >> 4;
  const int i0 = wv * 8;

  unsigned offA[8];
#pragma unroll
  for (int j = 0; j < 8; ++j) {
    int pos = (i0 + j) * 16 + (lane >> 2);
    int h = pos / Wp;
    int wc = pos - h * Wp - 1;
    int ar = rowlo + h;
    int pl = (lane & 3) ^ ((pos >> 1) & 3);
    bool ok = (ar >= 0) & (ar < H) & (wc >= 0) & (wc < W);
    offA[j] = ok ? (so + (unsigned)(ar * W + wc) * 512u + (unsigned)pl * 16u)
                 : (zpoff + (unsigned)(lane & 3) * 16u);
  }

  int pos0[4], fvalid[4];
#pragma unroll
  for (int f = 0; f < 4; ++f) {
    int fg = wm * 4 + f;
    fvalid[f] = (fg * 16 < npx);
    int p = p0 + fg * 16 + la; if (p > pend) p = pend;
    int h = p / W;
    pos0[f] = (h - rowlo) * Wp + (p - h * W + 1);
  }

  int boff[4];
#pragma unroll
  for (int nj = 0; nj < 4; ++nj) {
    int co = wn * 64 + nj * 16 + la;
    boff[nj] = (co << 6) + ((kg << 4) ^ (((co >> 1) & 3) << 4));
  }

  const char* bq = wnt + wv * 2048 + lane * 16;
  char* bd = (char*)ldsB + wv * 2048;

#define ISSUE_AO() do { _Pragma("unroll") \
    for (int j = 0; j < 8; ++j) { glds16(wsbase + offA[j], (char*)ldsA + (i0 + j) * 1024); offA[j] += 64u; } } while (0)
#define ISSUE_BO(q_, buf_) do { const char* s_ = bq + (q_) * 8192; \
    char* d_ = bd + (buf_) * 8192; \
    glds16(s_, d_); glds16(s_ + 1024, d_ + 1024); } while (0)

  ISSUE_AO();
  ISSUE_BO(0, 0);
  int pb = 0;

  for (int cc = 0; cc < 8; ++cc) {
#pragma unroll
    for (int tap = 0; tap < 9; ++tap) {
      __syncthreads();
      int q = cc * 9 + tap;
      if (q < 71) ISSUE_BO(q + 1, pb ^ 1);
      v8bf bfr[4];
#pragma unroll
      for (int nj = 0; nj < 4; ++nj) bfr[nj] = *(const v8bf*)((const char*)ldsB + pb * 8192 + boff[nj]);
      const int dh = tap / 3 - 1, dw = tap % 3 - 1;
      const int dt = dh * Wp + dw;
      v8bf afr[4];
#pragma unroll
      for (int f = 0; f < 4; ++f)
        if (fvalid[f]) {
          int pos = pos0[f] + dt;
          afr[f] = *(const v8bf*)((const char*)ldsA + ((pos << 6) + ((kg << 4) ^ (((pos >> 1) & 3) << 4))));
        }
#pragma unroll
      for (int f = 0; f < 4; ++f)
        if (fvalid[f])
#pragma unroll
          for (int nj = 0; nj < 4; ++nj)
            acc[f][nj] = __builtin_amdgcn_mfma_f32_16x16x32_bf16(afr[f], bfr[nj], acc[f][nj], 0, 0, 0);
      pb ^= 1;
      if (tap == 8 && cc < 7) { __syncthreads(); ISSUE_AO(); }
    }
  }
#undef ISSUE_AO
#undef ISSUE_BO
}

// ---------------- tower conv (96px, R4 kernel), dual-branch ----------------
__global__ __launch_bounds__(256, 2)
void conv_tower(const char* __restrict__ wsbase,
                unsigned so0, __bf16* __restrict__ dst0, const __bf16* __restrict__ w0, const float* __restrict__ b0,
                unsigned so1, __bf16* __restrict__ dst1, const __bf16* __restrict__ w1, const float* __restrict__ b1,
                unsigned zpoff, int half)
{
  int bid = blockIdx.x;
  int br = bid >= half;
  bid -= br ? half : 0;
  unsigned soff = br ? so1 : so0;
  __bf16* dst = br ? dst1 : dst0;
  const __bf16* wt = br ? w1 : w0;
  const float* bias = br ? b1 : b0;

  int x = bid & 7, slot = bid >> 3;        // XCD swizzle: nt twins colocated
  int nt = slot & 1, mtl = slot >> 1;      // mtl 0..70
  int mt = x + (mtl << 3);                 // 0..567
  int n = mt / 142, r = mt - n * 142;
  Geo g = decode96(r);
  int p0 = g.t * 96;
  int npx = g.HW - p0; if (npx > 96) npx = 96;
  unsigned so = soff + (unsigned)(g.pbase + n * g.HW) * 512u;

  f32x4 acc[3][4];
#pragma unroll
  for (int f = 0; f < 3; ++f)
#pragma unroll
    for (int j = 0; j < 4; ++j)
#pragma unroll
      for (int k = 0; k < 4; ++k) acc[f][j][k] = 0.0f;

  conv_core_t(wsbase, so, zpoff, (const char*)(wt + nt * 294912), g.W, g.H, p0, npx, acc);

  int lane = threadIdx.x & 63, wv = threadIdx.x >> 6;
  int wm = wv >> 1, wn = wv & 1, la = lane & 15, kg = lane >> 4;
  size_t pixbase = (size_t)(g.pbase + n * g.HW + p0);
#pragma unroll
  for (int f = 0; f < 3; ++f) {
    int fg = wm * 3 + f;
    if (fg * 16 < npx) {
#pragma unroll
      for (int nj = 0; nj < 4; ++nj) {
        int cob = nt * 128 + wn * 64 + nj * 16 + la;
        float bs = bias[cob];
#pragma unroll
        for (int rr = 0; rr < 4; ++rr) {
          int pl = fg * 16 + kg * 4 + rr;
          if (pl < npx)
            dst[((pixbase + pl) << 8) + cob] = (__bf16)fmaxf(acc[f][nj][rr] + bs, 0.0f);
        }
      }
    }
  }
}

// -------- cls out conv (128px, R2 kernel), grid 2568, XCD-chunked --------
__global__ __launch_bounds__(256, 3)
void conv_cls_out(const char* __restrict__ wsbase, unsigned soA,
                  float* __restrict__ out, const __bf16* __restrict__ wco,
                  const float* __restrict__ bco, unsigned zpoff)
{
  // bijective XCD chunking: 2568 = 8 * 321; the 6 nt-siblings of each
  // A-tile run back-to-back on one XCD (A hot in that XCD's L2).
  int bid0 = blockIdx.x;
  int bid = (bid0 & 7) * 321 + (bid0 >> 3);
  int nt = bid % 6, mt = bid / 6;
  int n = mt / 107, r = mt - n * 107;
  Geo g = decode128(r);
  int p0 = g.t << 7;
  int npx = g.HW - p0; if (npx > 128) npx = 128;
  unsigned so = soA + (unsigned)(g.pbase + n * g.HW) * 512u;

  f32x4 acc[4][4];
#pragma unroll
  for (int f = 0; f < 4; ++f)
#pragma unroll
    for (int j = 0; j < 4; ++j)
#pragma unroll
      for (int k = 0; k < 4; ++k) acc[f][j][k] = 0.0f;

  conv_core_o(wsbase, so, zpoff, (const char*)(wco + nt * 294912), g.W, g.H, p0, npx, acc);

  int lane = threadIdx.x & 63, wv = threadIdx.x >> 6;
  int wm = wv >> 1, wn = wv & 1, la = lane & 15, kg = lane >> 4;
#pragma unroll
  for (int f = 0; f < 4; ++f) {
    int fg = wm * 4 + f;
    if (fg * 16 < npx) {
#pragma unroll
      for (int nj = 0; nj < 4; ++nj) {
        int cob = nt * 128 + wn * 64 + nj * 16 + la;
        if (cob < 720) {
          float bs = bco[cob];
#pragma unroll
          for (int rr = 0; rr < 4; ++rr) {
            int pl = fg * 16 + kg * 4 + rr;
            if (pl < npx) {
              int pix = p0 + pl;
              out[(size_t)n * 9606960 + g.obC + (size_t)pix * 720 + cob] = acc[f][nj][rr] + bs;
            }
          }
        }
      }
    }
  }
}

// ---------------- reg out conv (128px, R2 kernel), grid 428 ----------------
__global__ __launch_bounds__(256, 3)
void conv_reg_out(const char* __restrict__ wsbase, unsigned soA,
                  float* __restrict__ out, const __bf16* __restrict__ wro,
                  const float* __restrict__ bro, unsigned zpoff)
{
  int mt = blockIdx.x;
  int n = mt / 107, r = mt - n * 107;
  Geo g = decode128(r);
  int p0 = g.t << 7;
  int npx = g.HW - p0; if (npx > 128) npx = 128;
  unsigned so = soA + (unsigned)(g.pbase + n * g.HW) * 512u;

  f32x4 acc[4][4];
#pragma unroll
  for (int f = 0; f < 4; ++f)
#pragma unroll
    for (int j = 0; j < 4; ++j)
#pragma unroll
      for (int k = 0; k < 4; ++k) acc[f][j][k] = 0.0f;

  conv_core_o(wsbase, so, zpoff, (const char*)wro, g.W, g.H, p0, npx, acc);

  int lane = threadIdx.x & 63, wv = threadIdx.x >> 6;
  int wm = wv >> 1, wn = wv & 1, la = lane & 15, kg = lane >> 4;
#pragma unroll
  for (int f = 0; f < 4; ++f) {
    int fg = wm * 4 + f;
    if (fg * 16 < npx) {
#pragma unroll
      for (int nj = 0; nj < 4; ++nj) {
        int cob = wn * 64 + nj * 16 + la;
        if (cob < 36) {
#pragma unroll
          for (int rr = 0; rr < 4; ++rr) {
            int pl = fg * 16 + kg * 4 + rr;
            if (pl < npx) {
              int pix = p0 + pl;
              out[38427840 + (size_t)n * 480348 + g.obR + (size_t)pix * 36 + cob] = acc[f][nj][rr] + bro[cob];
            }
          }
        }
      }
    }
  }
}

extern "C" void kernel_launch(void* const* d_in, const int* in_sizes, int n_in,
                              void* d_out, int out_size, void* d_ws, size_t ws_size,
                              hipStream_t stream) {
  (void)in_sizes; (void)n_in; (void)out_size;
  const float* feat0 = (const float*)d_in[0];
  const float* feat1 = (const float*)d_in[1];
  const float* feat2 = (const float*)d_in[2];
  const float* feat3 = (const float*)d_in[3];
  const float* feat4 = (const float*)d_in[4];
  const float* cls_w  = (const float*)d_in[5];
  const float* cls_b  = (const float*)d_in[6];
  const float* cls_ow = (const float*)d_in[7];
  const float* cls_ob = (const float*)d_in[8];
  const float* reg_w  = (const float*)d_in[9];
  const float* reg_b  = (const float*)d_in[10];
  const float* reg_ow = (const float*)d_in[11];
  const float* reg_ob = (const float*)d_in[12];
  float* out = (float*)d_out;

  const size_t ACT = 13663232;             // bf16 elems per activation tensor
  const size_t WSEG = 6782976;             // packed weights total elems
  const char* wsbase = (const char*)d_ws;
  __bf16* base = (__bf16*)d_ws;

  bool fused = ws_size >= (5 * ACT + WSEG + 4096) * 2;
  int nact = fused ? 5 : 3;
  __bf16* A = base + ACT;
  __bf16* B = base + 2 * ACT;
  __bf16* C = fused ? base + 3 * ACT : A;
  __bf16* D = fused ? base + 4 * ACT : B;
  __bf16* wb = base + nact * ACT;

  __bf16* w_cls[4], *w_reg[4];
  for (int li = 0; li < 4; ++li) { w_cls[li] = wb + (size_t)li * 589824; w_reg[li] = wb + (size_t)(4 + li) * 589824; }
  __bf16* wco = wb + 8 * 589824;
  __bf16* wro = wco + 1769472;
  __bf16* zp = wro + 294912;

  unsigned off_in = 0;
  unsigned off_A = (unsigned)(ACT * 2);
  unsigned off_B = (unsigned)(ACT * 4);
  unsigned off_C = fused ? (unsigned)(ACT * 6) : off_A;
  unsigned off_D = fused ? (unsigned)(ACT * 8) : off_B;
  unsigned off_zp = (unsigned)((nact * ACT + WSEG) * 2);

  hipMemsetAsync(zp, 0, 8192, stream);
  prep_in<<<6688, 256, 0, stream>>>(feat0, feat1, feat2, feat3, feat4, base);
  prep_w_all<<<3312, 256, 0, stream>>>(cls_w, reg_w, cls_ow, reg_ow, wb);

  if (fused) {
    conv_tower<<<2272, 256, 0, stream>>>(wsbase, off_in, A, w_cls[0], cls_b + 0,   off_in, C, w_reg[0], reg_b + 0,   off_zp, 1136);
    conv_tower<<<2272, 256, 0, stream>>>(wsbase, off_A,  B, w_cls[1], cls_b + 256, off_C,  D, w_reg[1], reg_b + 256, off_zp, 1136);
    conv_tower<<<2272, 256, 0, stream>>>(wsbase, off_B,  A, w_cls[2], cls_b + 512, off_D,  C, w_reg[2], reg_b + 512, off_zp, 1136);
    // L4: reg half FIRST, cls half SECOND -> cls-out input (B) written last
    conv_tower<<<2272, 256, 0, stream>>>(wsbase, off_C,  D, w_reg[3], reg_b + 768, off_A,  B, w_cls[3], cls_b + 768, off_zp, 1136);
    conv_cls_out<<<2568, 256, 0, stream>>>(wsbase, off_B, out, wco, cls_ob, off_zp);
    conv_reg_out<<<428, 256, 0, stream>>>(wsbase, off_D, out, wro, reg_ob, off_zp);
  } else {
    conv_tower<<<1136, 256, 0, stream>>>(wsbase, off_in, A, w_cls[0], cls_b + 0,   off_in, A, w_cls[0], cls_b, off_zp, 1136);
    conv_tower<<<1136, 256, 0, stream>>>(wsbase, off_A,  B, w_cls[1], cls_b + 256, off_A,  B, w_cls[1], cls_b, off_zp, 1136);
    conv_tower<<<1136, 256, 0, stream>>>(wsbase, off_B,  A, w_cls[2], cls_b + 512, off_B,  A, w_cls[2], cls_b, off_zp, 1136);
    conv_tower<<<1136, 256, 0, stream>>>(wsbase, off_A,  B, w_cls[3], cls_b + 768, off_A,  B, w_cls[3], cls_b, off_zp, 1136);
    conv_cls_out<<<2568, 256, 0, stream>>>(wsbase, off_B, out, wco, cls_ob, off_zp);
    conv_tower<<<1136, 256, 0, stream>>>(wsbase, off_in, A, w_reg[0], reg_b + 0,   off_in, A, w_reg[0], reg_b, off_zp, 1136);
    conv_tower<<<1136, 256, 0, stream>>>(wsbase, off_A,  B, w_reg[1], reg_b + 256, off_A,  B, w_reg[1], reg_b, off_zp, 1136);
    conv_tower<<<1136, 256, 0, stream>>>(wsbase, off_B,  A, w_reg[2], reg_b + 512, off_B,  A, w_reg[2], reg_b, off_zp, 1136);
    conv_tower<<<1136, 256, 0, stream>>>(wsbase, off_A,  B, w_reg[3], reg_b + 768, off_A,  B, w_reg[3], reg_b, off_zp, 1136);
    conv_reg_out<<<428, 256, 0, stream>>>(wsbase, off_B, out, wro, reg_ob, off_zp);
  }
}